// Round 9
// baseline (3107.685 us; speedup 1.0000x reference)
//
#include <hip/hip_runtime.h>
#include <stdint.h>

typedef unsigned short u16;
typedef unsigned int u32;
typedef unsigned long long u64;

#define B_ 64
#define T_ 512
#define N_ 128
#define H_ 512
#define KDIM 640        // H + N
#define FL 32           // u32 per 128B line
// sync lines: [0..7] org counters (agent); [8..15] per-XCD epoch counters

typedef __attribute__((ext_vector_type(8))) short short8;
typedef __attribute__((ext_vector_type(4))) float floatx4;

__device__ __forceinline__ float sigf(float x) { return 1.0f / (1.0f + __expf(-x)); }
__device__ __forceinline__ float tanh_(float x) { return 1.0f - 2.0f / (1.0f + __expf(2.0f * x)); }

__device__ __forceinline__ u16 f2bf(float x) {
    u32 u = __float_as_uint(x);
    u32 r = (u + 0x7FFFu + ((u >> 16) & 1u)) >> 16;   // RNE
    return (u16)r;
}

// X [B,T,N] fp32 -> Xb [T,B,N] bf16
__global__ __launch_bounds__(256) void k_xb(const float* __restrict__ X, u16* __restrict__ Xb) {
    int i = blockIdx.x * 256 + threadIdx.x;
    int n = i & 127, b = (i >> 7) & 63, t = i >> 13;
    Xb[i] = f2bf(X[(b * T_ + t) * N_ + n]);
}

// Wcat^T [2048 cols][640 k] bf16: rows k<512 from Wh, k>=512 from Wx
__global__ __launch_bounds__(256) void k_wcat(const float* __restrict__ Wx, const float* __restrict__ Wh,
                                              u16* __restrict__ Wt) {
    int i = blockIdx.x * 256 + threadIdx.x;
    int c = i & 2047, k = i >> 11;
    float v = (k < H_) ? Wh[k * 2048 + c] : Wx[(k - H_) * 2048 + c];
    Wt[c * KDIM + k] = f2bf(v);
}

// Batch-per-XCD LSTM, 8 WGs x 512 threads per XCD (4x fewer sync participants
// than R8). WG slot s owns h-cols [64s,64s+64); wave wv owns 8 h-cols
// (= 2 MFMA N-tiles of 16 gate-cols) -> gate math is WAVE-PRIVATE.
// Per step per XCD: 8 producer atomic-incs on ONE line + 8 poller lanes
// (RMW-return, hot; RT-paced). One __syncthreads per step.
// h-cols of a WG = one 128B line per batch -> no cross-CU L1 staleness.
__global__ __launch_bounds__(512, 2) void k_lstm(const u16* __restrict__ Wt, const u16* __restrict__ Xb,
                                                 u16* __restrict__ hs, const float* __restrict__ bias,
                                                 u32* __restrict__ sync) {
    __shared__ u16 sWx[256 * 136];     // Wx slice: 256 gate-cols x 128 K (+pad), 69632B
    __shared__ float sG[8 * 264];      // per-wave 8 rows x 33 fp32, 8448B
    __shared__ int sSlot, sXcc, sEpoch;

    const int tid = threadIdx.x;
    const int lane = tid & 63, wv = tid >> 6;       // wv in [0,8)
    const int l16 = lane & 15, quad = lane >> 4;

    // ---- one-time: XCD self-organization (R7/R8-proven) ----
    if (tid == 0) {
        u32 xcc;
        asm volatile("s_getreg_b32 %0, hwreg(HW_REG_XCC_ID)" : "=s"(xcc));
        xcc &= 7;
        u32 slot = __hip_atomic_fetch_add(sync + xcc * FL, 1u, __ATOMIC_RELAXED, __HIP_MEMORY_SCOPE_AGENT);
        int ok = -1;
        if (slot < 8) {
            int g = 0;
            while (__hip_atomic_load(sync + xcc * FL, __ATOMIC_RELAXED, __HIP_MEMORY_SCOPE_AGENT) < 8u) {
                __builtin_amdgcn_s_sleep(8);
                if (++g > 2000000) { ok = -2; break; }
            }
            if (ok == -1) ok = (int)slot;
        }
        sSlot = ok; sXcc = (int)xcc; sEpoch = 0;
    }
    __syncthreads();
    const int s = sSlot;
    if (s < 0) return;                  // extra WG / (never-seen) incomplete XCD
    const int xcc = sXcc;
    const int b0 = 8 * xcc;             // this XCD's batch base

    // per-lane gate biases (gate math lane -> hcol j = lane&7)
    float bv0, bv1, bv2, bv3;
    {
        int hc = s * 64 + wv * 8 + (lane & 7);
        bv0 = bias[hc]; bv1 = bias[512 + hc];
        bv2 = bias[1024 + hc] + 1.0f;              // forget_bias
        bv3 = bias[1536 + hc];
    }

    // Wh fragments in VGPRs: tile n covers gate-cols g*4..g*4+3 -> hcol sub n*4+(c&3)
    short8 bfr0[16], bfr1[16];
    {
        size_t col0 = (size_t)(l16 >> 2) * 512 + s * 64 + wv * 8 + (l16 & 3);
        const u16* w0 = Wt + col0 * KDIM + quad * 8;
        const u16* w1 = Wt + (col0 + 4) * KDIM + quad * 8;
#pragma unroll
        for (int ks = 0; ks < 16; ++ks) {
            bfr0[ks] = *(const short8*)(w0 + ks * 32);
            bfr1[ks] = *(const short8*)(w1 + ks * 32);
        }
    }
    // Wx slice -> LDS (per-step ds_read instead of 32 more VGPRs)
    for (int u = tid; u < 4096; u += 512) {
        int lcol = u >> 4, kc = u & 15;
        int gc = (lcol >> 6) * 512 + s * 64 + (lcol & 63);
        *(short8*)(sWx + lcol * 136 + kc * 8) =
            *(const short8*)(Wt + (size_t)gc * KDIM + 512 + kc * 8);
    }
    __syncthreads();

    const u16* wx0 = sWx + ((l16 >> 2) * 64 + wv * 8 + (l16 & 3)) * 136 + quad * 8;
    const u16* wx1 = wx0 + 4 * 136;
    u32* ep = sync + (size_t)(8 + xcc) * FL;
    const int bA = l16 & 7;             // A-frag batch row (rows 8..15 duplicate)
    float cst = 0.f;                    // cell state: lane owns (b=lane>>3, j=lane&7)

    for (int t = 0; t < T_; ++t) {
        // x fragments: recurrence-independent -> issue before the wait
        short8 xfr[4];
        const u16* xrow = Xb + ((size_t)t * 64 + b0 + bA) * N_ + quad * 8;
#pragma unroll
        for (int ks = 0; ks < 4; ++ks) xfr[ks] = *(const short8*)(xrow + ks * 32);

        if (t > 0) {
            if (wv == 0) {
                if (lane == 0) {
                    const u32 thr = 8u * (u32)t;
                    int g = 0;
                    for (;;) {
                        u32 old, zero = 0;
                        asm volatile("global_atomic_add %0, %1, %2, off sc0\n\ts_waitcnt vmcnt(0)"
                                     : "=v"(old) : "v"(ep), "v"(zero) : "memory");
                        if (old >= thr) break;
                        if (++g > 300000) break;   // fail-safe: never hang
                    }
                    __hip_atomic_store(&sEpoch, t, __ATOMIC_RELAXED, __HIP_MEMORY_SCOPE_WORKGROUP);
                }
                // wave0 reconverges here; lanes 1-63 ordered after lane0's poll
            } else {
                int g = 0;
                while (__hip_atomic_load(&sEpoch, __ATOMIC_RELAXED, __HIP_MEMORY_SCOPE_WORKGROUP) < t) {
                    __builtin_amdgcn_s_sleep(1);
                    if (++g > 3000000) break;
                }
            }
            asm volatile("" ::: "memory");
        }

        // h fragments from this XCD's L2 (fresh addresses; own-line writes only)
        short8 afr[16];
        const u16* hrow = hs + ((size_t)t * 64 + b0 + bA) * H_ + quad * 8;
#pragma unroll
        for (int ks = 0; ks < 16; ++ks) afr[ks] = *(const short8*)(hrow + ks * 32);

        // GEMM: M=16 (8 batches dup), 2 N-tiles of 16 gate-cols, K=512(h)+128(x)
        floatx4 a0 = {0.f,0.f,0.f,0.f}, a1 = {0.f,0.f,0.f,0.f};
#pragma unroll
        for (int ks = 0; ks < 16; ++ks) {
            a0 = __builtin_amdgcn_mfma_f32_16x16x32_bf16(afr[ks], bfr0[ks], a0, 0, 0, 0);
            a1 = __builtin_amdgcn_mfma_f32_16x16x32_bf16(afr[ks], bfr1[ks], a1, 0, 0, 0);
        }
#pragma unroll
        for (int k2 = 0; k2 < 4; ++k2) {
            short8 wb0 = *(const short8*)(wx0 + k2 * 32);
            short8 wb1 = *(const short8*)(wx1 + k2 * 32);
            a0 = __builtin_amdgcn_mfma_f32_16x16x32_bf16(xfr[k2], wb0, a0, 0, 0, 0);
            a1 = __builtin_amdgcn_mfma_f32_16x16x32_bf16(xfr[k2], wb1, a1, 0, 0, 0);
        }

        // wave-private gate exchange: C/D row = quad*4+r (rows 0..7 real), col = l16
        if (quad < 2) {
            float* gb = sG + wv * 264 + (quad * 4) * 33 + l16;
#pragma unroll
            for (int r = 0; r < 4; ++r) { gb[r * 33] = a0[r]; gb[r * 33 + 16] = a1[r]; }
        }
        asm volatile("s_waitcnt lgkmcnt(0)" ::: "memory");

        // gate math (intra-wave): lane -> batch b=lane>>3, hcol j=lane&7
        {
            int b = lane >> 3, j = lane & 7;
            const float* gr = sG + wv * 264 + b * 33 + ((j >> 2) << 4) + (j & 3);
            float gi = gr[0] + bv0;
            float gj = gr[4] + bv1;
            float gf = gr[8] + bv2;
            float go = gr[12] + bv3;
            cst = sigf(gf) * cst + sigf(gi) * tanh_(gj);
            float h = sigf(go) * tanh_(cst);
            hs[((size_t)(t + 1) * 64 + b0 + b) * H_ + s * 64 + wv * 8 + j] = f2bf(h);
        }

        // drain h to L2, join 8 waves, single per-WG epoch increment
        asm volatile("s_waitcnt vmcnt(0)" ::: "memory");
        __syncthreads();
        if (tid == 0) {
            u32 one = 1;
            asm volatile("global_atomic_add %0, %1, off" :: "v"(ep), "v"(one) : "memory");
        }
    }
}

// decoder + loss: rows R = t*64+b of hs[1..512]; 32 rows/block staged in LDS
__global__ __launch_bounds__(256) void k_dec(const u16* __restrict__ hs, const float* __restrict__ Wd,
                                             const float* __restrict__ bd, const float* __restrict__ Y,
                                             float* __restrict__ out) {
    __shared__ u16 sH[32 * H_];
    __shared__ float red[4];
    int tid = threadIdx.x;
    int R0 = blockIdx.x * 32;
    for (int u = tid; u < 2048; u += 256) {
        int row = u >> 6, ch = u & 63;
        *(short8*)(sH + row * H_ + ch * 8) =
            *(const short8*)(hs + (size_t)(64 + R0 + row) * H_ + ch * 8);
    }
    __syncthreads();

    int n = tid & 127, half = tid >> 7;
    float bdv = bd[n];
    float acc[16];
#pragma unroll
    for (int i = 0; i < 16; ++i) acc[i] = 0.f;

    for (int ko = 0; ko < H_ / 8; ++ko) {
        float wv[8];
#pragma unroll
        for (int j = 0; j < 8; ++j) wv[j] = Wd[(ko * 8 + j) * N_ + n];
#pragma unroll
        for (int i = 0; i < 16; ++i) {
            int r = half * 16 + i;
            const uint4 hv = *(const uint4*)(sH + r * H_ + ko * 8);
            acc[i] += __uint_as_float(hv.x << 16) * wv[0] + __uint_as_float(hv.x & 0xFFFF0000u) * wv[1]
                    + __uint_as_float(hv.y << 16) * wv[2] + __uint_as_float(hv.y & 0xFFFF0000u) * wv[3]
                    + __uint_as_float(hv.z << 16) * wv[4] + __uint_as_float(hv.z & 0xFFFF0000u) * wv[5]
                    + __uint_as_float(hv.w << 16) * wv[6] + __uint_as_float(hv.w & 0xFFFF0000u) * wv[7];
        }
    }
    float sse = 0.f;
#pragma unroll
    for (int i = 0; i < 16; ++i) {
        int R = R0 + half * 16 + i;
        int t = R >> 6, b = R & 63;
        float logit = sigf(acc[i] + bdv);
        float d = Y[(size_t)(b * T_ + t) * N_ + n] - logit;
        sse += d * d;
    }
    for (int off = 32; off > 0; off >>= 1) sse += __shfl_down(sse, off, 64);
    if ((tid & 63) == 0) red[tid >> 6] = sse;
    __syncthreads();
    if (tid == 0) {
        float tot = red[0] + red[1] + red[2] + red[3];
        atomicAdd(out, tot * (100.0f / 4194304.0f));
    }
}

extern "C" void kernel_launch(void* const* d_in, const int* in_sizes, int n_in,
                              void* d_out, int out_size, void* d_ws, size_t ws_size,
                              hipStream_t stream) {
    (void)in_sizes; (void)n_in; (void)out_size;
    const float* X  = (const float*)d_in[0];
    const float* Y  = (const float*)d_in[1];
    const float* Wx = (const float*)d_in[2];
    const float* Wh = (const float*)d_in[3];
    const float* bb = (const float*)d_in[4];
    const float* Wd = (const float*)d_in[5];
    const float* bd = (const float*)d_in[6];

    char* ws = (char*)d_ws;
    u32* syncz = (u32*)ws;
    const size_t sync_bytes = 131072;
    u16* hs  = (u16*)(ws + sync_bytes);
    const size_t hs_bytes = (size_t)(T_ + 1) * 64 * H_ * 2;   // 33,619,968
    u16* Xb  = (u16*)(ws + sync_bytes + hs_bytes);
    const size_t xb_bytes = (size_t)T_ * 64 * N_ * 2;         // 8,388,608
    u16* Wt  = (u16*)(ws + sync_bytes + hs_bytes + xb_bytes);
    const size_t need = sync_bytes + hs_bytes + xb_bytes + (size_t)2048 * KDIM * 2;
    if (ws_size < need) return;   // ~44.8 MB scratch required

    (void)hipMemsetAsync(syncz, 0, 5120, stream);             // org + epoch counters
    (void)hipMemsetAsync(hs, 0, 64 * H_ * 2, stream);         // h_{-1} = 0
    (void)hipMemsetAsync(d_out, 0, sizeof(float), stream);

    k_xb<<<dim3((B_ * T_ * N_) / 256), dim3(256), 0, stream>>>(X, Xb);
    k_wcat<<<dim3((2048 * KDIM) / 256), dim3(256), 0, stream>>>(Wx, Wh, Wt);

    void* args[] = { (void*)&Wt, (void*)&Xb, (void*)&hs, (void*)&bb, (void*)&syncz };
    (void)hipLaunchCooperativeKernel((const void*)k_lstm, dim3(256), dim3(512), args, 0, stream);

    k_dec<<<dim3((B_ * T_) / 32), dim3(256), 0, stream>>>(hs, Wd, bd, Y, (float*)d_out);
}

// Round 10
// 2331.954 us; speedup vs baseline: 1.3327x; 1.3327x over previous
//
#include <hip/hip_runtime.h>
#include <stdint.h>

typedef unsigned short u16;
typedef unsigned int u32;
typedef unsigned long long u64;

#define B_ 64
#define T_ 512
#define N_ 128
#define H_ 512
#define KDIM 640        // H + N
#define FL 32           // u32 per 128B line
// sync lines: [0..7] org counters (agent) | [8 + xcc*4 + i] producer counters (L2)
//             [40 + xcc*32 + s] mailboxes (L2)

typedef __attribute__((ext_vector_type(8))) short short8;
typedef __attribute__((ext_vector_type(4))) float floatx4;

__device__ __forceinline__ float sigf(float x) { return 1.0f / (1.0f + __expf(-x)); }
__device__ __forceinline__ float tanh_(float x) { return 1.0f - 2.0f / (1.0f + __expf(2.0f * x)); }

__device__ __forceinline__ u16 f2bf(float x) {
    u32 u = __float_as_uint(x);
    u32 r = (u + 0x7FFFu + ((u >> 16) & 1u)) >> 16;   // RNE
    return (u16)r;
}

// ~64-cycle dependent-FMA chain: paces hot spin loops AND keeps VALU activity
// high so the SMU doesn't park the engine clock at idle (R10 core hypothesis:
// R5/R8/R9 all floor at ~5 us/step because s_sleep-heavy, ~2%-active kernels
// run at the ~500 MHz idle clock — 4.9x off the 2.4 GHz models).
__device__ __forceinline__ void heat(float& hf) {
#pragma unroll
    for (int i = 0; i < 16; ++i) hf = __builtin_fmaf(hf, 1.0000001f, 1e-30f);
    asm volatile("" : "+v"(hf));
}

// X [B,T,N] fp32 -> Xb [T,B,N] bf16
__global__ __launch_bounds__(256) void k_xb(const float* __restrict__ X, u16* __restrict__ Xb) {
    int i = blockIdx.x * 256 + threadIdx.x;
    int n = i & 127, b = (i >> 7) & 63, t = i >> 13;
    Xb[i] = f2bf(X[(b * T_ + t) * N_ + n]);
}

// Wcat^T [2048 cols][640 k] bf16: rows k<512 from Wh, k>=512 from Wx
__global__ __launch_bounds__(256) void k_wcat(const float* __restrict__ Wx, const float* __restrict__ Wh,
                                              u16* __restrict__ Wt) {
    int i = blockIdx.x * 256 + threadIdx.x;
    int c = i & 2047, k = i >> 11;
    float v = (k < H_) ? Wh[k * 2048 + c] : Wx[(k - H_) * 2048 + c];
    Wt[c * KDIM + k] = f2bf(v);
}

// Batch-per-XCD LSTM (R8 skeleton), hot-clock edition. See R10 notes above.
__global__ __launch_bounds__(256, 1) void k_lstm(const u16* __restrict__ Wt, const u16* __restrict__ Xb,
                                                 u16* __restrict__ hs, const float* __restrict__ bias,
                                                 u32* __restrict__ sync) {
    __shared__ float sG[4 * 136];      // per-wave 8 rows x 16 cols (pitch 17)
    __shared__ int sSlot, sXcc, sEpoch;

    const int tid = threadIdx.x;
    const int lane = tid & 63, wv = tid >> 6;
    const int l16 = lane & 15, quad = lane >> 4;

    // ---- one-time: XCD self-organization (R7/R8-proven; sleep OK here) ----
    if (tid == 0) {
        u32 xcc;
        asm volatile("s_getreg_b32 %0, hwreg(HW_REG_XCC_ID)" : "=s"(xcc));
        xcc &= 7;
        u32 slot = __hip_atomic_fetch_add(sync + xcc * FL, 1u, __ATOMIC_RELAXED, __HIP_MEMORY_SCOPE_AGENT);
        int ok = -1;
        if (slot < 32) {
            int g = 0;
            while (__hip_atomic_load(sync + xcc * FL, __ATOMIC_RELAXED, __HIP_MEMORY_SCOPE_AGENT) < 32u) {
                __builtin_amdgcn_s_sleep(8);
                if (++g > 2000000) { ok = -2; break; }
            }
            if (ok == -1) ok = (int)slot;
        }
        sSlot = ok; sXcc = (int)xcc; sEpoch = 0;
    }
    __syncthreads();
    const int s = sSlot;
    if (s < 0) return;
    const int xcc = sXcc;
    const int b0 = 8 * xcc;

    // gate biases for gate-math lane (lane<16 -> batch lane>>1, cols j0=(lane&1)*2, j0+1)
    float biA, bjA, bfA, boA, biB, bjB, bfB, boB;
    {
        int j0 = (lane & 1) * 2;
        int hcA = s * 16 + wv * 4 + j0, hcB = hcA + 1;
        biA = bias[hcA]; bjA = bias[512 + hcA]; bfA = bias[1024 + hcA] + 1.0f; boA = bias[1536 + hcA];
        biB = bias[hcB]; bjB = bias[512 + hcB]; bfB = bias[1024 + hcB] + 1.0f; boB = bias[1536 + hcB];
    }

    // weight fragments: local col c=l16 -> global col (c>>2)*512 + s*16 + wv*4 + (c&3)
    short8 bfr[20];
    {
        size_t bcol = (size_t)(l16 >> 2) * 512 + s * 16 + wv * 4 + (l16 & 3);
        const u16* wp = Wt + bcol * KDIM + quad * 8;
#pragma unroll
        for (int ks = 0; ks < 20; ++ks) bfr[ks] = *(const short8*)(wp + ks * 32);
    }

    u32* cnt  = sync + (size_t)(8 + xcc * 4) * FL;
    u32* mbox = sync + (size_t)(40 + xcc * 32) * FL;
    const int bA = l16 & 7;
    float cstA = 0.f, cstB = 0.f;
    float hf = 1.0f;
    __syncthreads();

    for (int t = 0; t < T_; ++t) {
        // x fragments: recurrence-independent
        short8 xfr[4];
        const u16* xrow = Xb + ((size_t)t * 64 + b0 + bA) * N_ + quad * 8;
#pragma unroll
        for (int ks = 0; ks < 4; ++ks) xfr[ks] = *(const short8*)(xrow + ks * 32);

        if (t > 0) {
            if (wv == 0) {
                if (s == 0) {
                    // single hot poller per XCD: lanes 0-3 RMW the 4 counter lines
                    const u32 thr = 8u * (u32)t;
                    bool done = (lane >= 4);
                    u32* cl = cnt + (size_t)lane * FL;
                    int g = 0;
                    while (!__all(done)) {
                        if (!done) {
                            u32 old, zero = 0;
                            asm volatile("global_atomic_add %0, %1, %2, off sc0\n\ts_waitcnt vmcnt(0)"
                                         : "=v"(old) : "v"(cl), "v"(zero) : "memory");
                            done = (old >= thr);
                        }
                        heat(hf);
                        if (++g > 1000000) break;   // fail-safe
                    }
                    // fan-out to 32 mailboxes (plain stores -> L2), drain, LDS epoch
                    if (lane < 32) *(mbox + (size_t)lane * FL) = (u32)t;
                    asm volatile("s_waitcnt vmcnt(0)" ::: "memory");
                    if (lane == 0)
                        __hip_atomic_store(&sEpoch, t, __ATOMIC_RELAXED, __HIP_MEMORY_SCOPE_WORKGROUP);
                } else {
                    // mailbox owner: 1 writer + 1 reader per line -> hot RMW is safe
                    if (lane == 0) {
                        u32* mb = mbox + (size_t)s * FL;
                        int g = 0;
                        for (;;) {
                            u32 old, zero = 0;
                            asm volatile("global_atomic_add %0, %1, %2, off sc0\n\ts_waitcnt vmcnt(0)"
                                         : "=v"(old) : "v"(mb), "v"(zero) : "memory");
                            if (old >= (u32)t) break;
                            heat(hf);
                            if (++g > 1000000) break;   // fail-safe
                        }
                        __hip_atomic_store(&sEpoch, t, __ATOMIC_RELAXED, __HIP_MEMORY_SCOPE_WORKGROUP);
                    }
                }
            } else {
                // waves 1-3: hot LDS spin with heater
                int g = 0;
                while (__hip_atomic_load(&sEpoch, __ATOMIC_RELAXED, __HIP_MEMORY_SCOPE_WORKGROUP) < t) {
                    heat(hf);
                    if (++g > 3000000) break;   // fail-safe
                }
            }
            asm volatile("" ::: "memory");
        }

        // h fragments from this XCD's L2 (fresh addresses each t; R7/R8-proven)
        short8 afr[16];
        const u16* hrow = hs + ((size_t)t * 64 + b0 + bA) * H_ + quad * 8;
#pragma unroll
        for (int ks = 0; ks < 16; ++ks) afr[ks] = *(const short8*)(hrow + ks * 32);

        // GEMM: M=16 (8 real batches dup), one N-tile (16 gate-cols), K=640
        floatx4 p = {0.f,0.f,0.f,0.f}, q = {0.f,0.f,0.f,0.f};
#pragma unroll
        for (int ks = 0; ks < 16; ks += 2) {
            p = __builtin_amdgcn_mfma_f32_16x16x32_bf16(afr[ks],     bfr[ks],     p, 0, 0, 0);
            q = __builtin_amdgcn_mfma_f32_16x16x32_bf16(afr[ks + 1], bfr[ks + 1], q, 0, 0, 0);
        }
#pragma unroll
        for (int k2 = 0; k2 < 4; k2 += 2) {
            p = __builtin_amdgcn_mfma_f32_16x16x32_bf16(xfr[k2],     bfr[16 + k2],     p, 0, 0, 0);
            q = __builtin_amdgcn_mfma_f32_16x16x32_bf16(xfr[k2 + 1], bfr[16 + k2 + 1], q, 0, 0, 0);
        }
        floatx4 acc = p + q;

        // C/D: row = quad*4+r (rows 0..7 real), col = l16 -> wave-private sG
        if (quad < 2) {
            float* gb = sG + wv * 136 + (quad * 4) * 17 + l16;
#pragma unroll
            for (int r = 0; r < 4; ++r) gb[r * 17] = acc[r];
        }
        asm volatile("s_waitcnt lgkmcnt(0)" ::: "memory");

        // gate math (wave-private): lane<16 -> batch b=lane>>1, cols j0, j0+1
        if (lane < 16) {
            int b = lane >> 1, j0 = (lane & 1) * 2;
            const float* gr = sG + wv * 136 + b * 17;
            float giA = gr[j0]      + biA, giB = gr[j0 + 1]      + biB;
            float gjA = gr[4 + j0]  + bjA, gjB = gr[4 + j0 + 1]  + bjB;
            float gfA = gr[8 + j0]  + bfA, gfB = gr[8 + j0 + 1]  + bfB;
            float goA = gr[12 + j0] + boA, goB = gr[12 + j0 + 1] + boB;
            cstA = sigf(gfA) * cstA + sigf(giA) * tanh_(gjA);
            cstB = sigf(gfB) * cstB + sigf(giB) * tanh_(gjB);
            float hA = sigf(goA) * tanh_(cstA);
            float hB = sigf(goB) * tanh_(cstB);
            u32 pk = ((u32)f2bf(hB) << 16) | (u32)f2bf(hA);
            *(u32*)(hs + ((size_t)(t + 1) * 64 + b0 + b) * H_ + s * 16 + wv * 4 + j0) = pk;
        }

        // drain h to L2, join 4 waves, one producer inc on counter line (s&3)
        asm volatile("s_waitcnt vmcnt(0)" ::: "memory");
        __syncthreads();
        if (tid == 0) {
            u32 one = 1;
            u32* cl = cnt + (size_t)(s & 3) * FL;
            asm volatile("global_atomic_add %0, %1, off" :: "v"(cl), "v"(one) : "memory");
        }
    }
    (void)hf;
}

// decoder + loss: rows R = t*64+b of hs[1..512]; 32 rows/block staged in LDS
__global__ __launch_bounds__(256) void k_dec(const u16* __restrict__ hs, const float* __restrict__ Wd,
                                             const float* __restrict__ bd, const float* __restrict__ Y,
                                             float* __restrict__ out) {
    __shared__ u16 sH[32 * H_];
    __shared__ float red[4];
    int tid = threadIdx.x;
    int R0 = blockIdx.x * 32;
    for (int u = tid; u < 2048; u += 256) {
        int row = u >> 6, ch = u & 63;
        *(short8*)(sH + row * H_ + ch * 8) =
            *(const short8*)(hs + (size_t)(64 + R0 + row) * H_ + ch * 8);
    }
    __syncthreads();

    int n = tid & 127, half = tid >> 7;
    float bdv = bd[n];
    float acc[16];
#pragma unroll
    for (int i = 0; i < 16; ++i) acc[i] = 0.f;

    for (int ko = 0; ko < H_ / 8; ++ko) {
        float wv[8];
#pragma unroll
        for (int j = 0; j < 8; ++j) wv[j] = Wd[(ko * 8 + j) * N_ + n];
#pragma unroll
        for (int i = 0; i < 16; ++i) {
            int r = half * 16 + i;
            const uint4 hv = *(const uint4*)(sH + r * H_ + ko * 8);
            acc[i] += __uint_as_float(hv.x << 16) * wv[0] + __uint_as_float(hv.x & 0xFFFF0000u) * wv[1]
                    + __uint_as_float(hv.y << 16) * wv[2] + __uint_as_float(hv.y & 0xFFFF0000u) * wv[3]
                    + __uint_as_float(hv.z << 16) * wv[4] + __uint_as_float(hv.z & 0xFFFF0000u) * wv[5]
                    + __uint_as_float(hv.w << 16) * wv[6] + __uint_as_float(hv.w & 0xFFFF0000u) * wv[7];
        }
    }
    float sse = 0.f;
#pragma unroll
    for (int i = 0; i < 16; ++i) {
        int R = R0 + half * 16 + i;
        int t = R >> 6, b = R & 63;
        float logit = sigf(acc[i] + bdv);
        float d = Y[(size_t)(b * T_ + t) * N_ + n] - logit;
        sse += d * d;
    }
    for (int off = 32; off > 0; off >>= 1) sse += __shfl_down(sse, off, 64);
    if ((tid & 63) == 0) red[tid >> 6] = sse;
    __syncthreads();
    if (tid == 0) {
        float tot = red[0] + red[1] + red[2] + red[3];
        atomicAdd(out, tot * (100.0f / 4194304.0f));
    }
}

extern "C" void kernel_launch(void* const* d_in, const int* in_sizes, int n_in,
                              void* d_out, int out_size, void* d_ws, size_t ws_size,
                              hipStream_t stream) {
    (void)in_sizes; (void)n_in; (void)out_size;
    const float* X  = (const float*)d_in[0];
    const float* Y  = (const float*)d_in[1];
    const float* Wx = (const float*)d_in[2];
    const float* Wh = (const float*)d_in[3];
    const float* bb = (const float*)d_in[4];
    const float* Wd = (const float*)d_in[5];
    const float* bd = (const float*)d_in[6];

    char* ws = (char*)d_ws;
    u32* syncz = (u32*)ws;
    const size_t sync_bytes = 131072;
    u16* hs  = (u16*)(ws + sync_bytes);
    const size_t hs_bytes = (size_t)(T_ + 1) * 64 * H_ * 2;   // 33,619,968
    u16* Xb  = (u16*)(ws + sync_bytes + hs_bytes);
    const size_t xb_bytes = (size_t)T_ * 64 * N_ * 2;         // 8,388,608
    u16* Wt  = (u16*)(ws + sync_bytes + hs_bytes + xb_bytes);
    const size_t need = sync_bytes + hs_bytes + xb_bytes + (size_t)2048 * KDIM * 2;
    if (ws_size < need) return;   // ~44.8 MB scratch required

    (void)hipMemsetAsync(syncz, 0, 65536, stream);            // org + counters + mailboxes
    (void)hipMemsetAsync(hs, 0, 64 * H_ * 2, stream);         // h_{-1} = 0
    (void)hipMemsetAsync(d_out, 0, sizeof(float), stream);

    k_xb<<<dim3((B_ * T_ * N_) / 256), dim3(256), 0, stream>>>(X, Xb);
    k_wcat<<<dim3((2048 * KDIM) / 256), dim3(256), 0, stream>>>(Wx, Wh, Wt);

    void* args[] = { (void*)&Wt, (void*)&Xb, (void*)&hs, (void*)&bb, (void*)&syncz };
    (void)hipLaunchCooperativeKernel((const void*)k_lstm, dim3(256), dim3(256), args, 0, stream);

    k_dec<<<dim3((B_ * T_) / 32), dim3(256), 0, stream>>>(hs, Wd, bd, Y, (float*)d_out);
}